// Round 9
// baseline (410.791 us; speedup 1.0000x reference)
//
#include <hip/hip_runtime.h>
#include <cstdint>
#include <math.h>

typedef unsigned int u32;
typedef unsigned long long u64;
typedef unsigned short ushort;

typedef __attribute__((ext_vector_type(8))) _Float16 f16x8;
typedef __attribute__((ext_vector_type(4))) _Float16 f16x4;
typedef __attribute__((ext_vector_type(4))) float f32x4;

#define NB    4
#define BnN   2048
#define NE    261632      // 512*511 ordered pairs per batch
#define NCHUNK 32
#define ECHUNK 8176       // NE/32 exactly
#define KEDGE 4096
#define TIECAP 2048
#define PSLICE 2359296    // 4*2304*256 elements per K-slice partial
#define MS    64          // meta stride (u32) per sel -> 256B, own cache lines
#define TS    64          // tiecnt stride (int) per sel

#define GLD16(gsrc, ldst)                                                    \
    __builtin_amdgcn_global_load_lds(                                        \
        (const __attribute__((address_space(1))) void*)(gsrc),               \
        (__attribute__((address_space(3))) void*)(ldst), 16, 0, 0)

// meta[sel*MS+i]: 0:p12  1:need1  2:qlo  3:qhi  4:wstar  5:emitcnt  6:prefix24  7:need2
// ---------------------------------------------------------------------------
// prep: fused cvt_x (3072 blocks) + cvt_w (256) + cvt_t5 (1472). One launch.
// ---------------------------------------------------------------------------
__global__ __launch_bounds__(256) void prep_kernel(
    const float* __restrict__ in, _Float16* __restrict__ xf,
    const float* __restrict__ W, _Float16* __restrict__ wf,
    const float* __restrict__ Wc,  _Float16* __restrict__ WcT,
    const float* __restrict__ Wgr, _Float16* __restrict__ WgrT,
    const float* __restrict__ Wgc, _Float16* __restrict__ WgcT,
    const float* __restrict__ Wr,  _Float16* __restrict__ WrT,
    const float* __restrict__ Wcc, _Float16* __restrict__ WccT)
{
    __shared__ _Float16 sh[9216];
    const int bid = blockIdx.x;
    const int tid = threadIdx.x;
    if (bid < 3072) {
        // ---- cvt_x: NCHW fp32 -> NHWC f16 ----
        _Float16 (*shx)[49] = (_Float16(*)[49])sh;
        int cg = bid & 15, rem = bid >> 4;
        int y = rem % 48, b = rem / 48;
        for (int i = tid; i < 64 * 48; i += 256) {
            int cl = i / 48, x = i - cl * 48;
            shx[cl][x] = (_Float16)in[(((size_t)b * 1024 + cg * 64 + cl) * 48 + y) * 48 + x];
        }
        __syncthreads();
        for (int i = tid; i < 64 * 48; i += 256) {
            int x = i / 64, cl = i - x * 64;
            xf[((size_t)(b * 48 + y) * 48 + x) * 1024 + cg * 64 + cl] = shx[cl][x];
        }
    } else if (bid < 3328) {
        // ---- cvt_w: [o][ch][3][3] fp32 -> [o][tap][ch] f16 ----
        int o = bid - 3072;
        for (int g = tid; g < 9216; g += 256)
            sh[g] = (_Float16)W[(size_t)o * 9216 + g];     // g = ch*9+tap
        __syncthreads();
        for (int g = tid; g < 9216; g += 256) {
            int tap = g >> 10, ch = g & 1023;
            wf[(size_t)o * 9216 + g] = sh[ch * 9 + tap];
        }
    } else {
        // ---- cvt_t5: 5 weight matrices fp32 [K][N] -> f16 [N][K] ----
        _Float16 (*sht)[33] = (_Float16(*)[33])sh;
        int b2 = bid - 3328;
        const float* inm; _Float16* outm; int K, N, tx0, ty0, ntx;
        if (b2 < 512)       { inm = Wc;  outm = WcT;  K = 1024; N = 512; ntx = 16; b2 -= 0;    }
        else if (b2 < 896)  { inm = Wgr; outm = WgrT; K = 768;  N = 512; ntx = 16; b2 -= 512;  }
        else if (b2 < 1280) { inm = Wgc; outm = WgcT; K = 768;  N = 512; ntx = 16; b2 -= 896;  }
        else if (b2 < 1408) { inm = Wr;  outm = WrT;  K = 512;  N = 228; ntx = 8;  b2 -= 1280; }
        else                { inm = Wcc; outm = WccT; K = 512;  N = 116; ntx = 4;  b2 -= 1408; }
        tx0 = (b2 % ntx) * 32;   // n0
        ty0 = (b2 / ntx) * 32;   // k0
        int tx = tid & 31, ty = tid >> 5;
#pragma unroll
        for (int i = 0; i < 4; ++i) {
            int k = ty0 + ty + i * 8, n = tx0 + tx;
            sht[ty + i * 8][tx] = (k < K && n < N) ? (_Float16)inm[(size_t)k * N + n] : (_Float16)0.f;
        }
        __syncthreads();
#pragma unroll
        for (int i = 0; i < 4; ++i) {
            int n = tx0 + ty + i * 8, k = ty0 + tx;
            if (n < N && k < K) outm[(size_t)n * K + k] = sht[tx][ty + i * 8];
        }
    }
}

// ---------------------------------------------------------------------------
// 256-thread edge-pipeline building blocks (bit-identical math/ordering to
// the 1024-thread originals; stride 256 instead of 1024).
// ---------------------------------------------------------------------------
__device__ __forceinline__ float sv_tb_256(
    const float* __restrict__ boxes, const float* __restrict__ scales,
    const float* __restrict__ pdls, const float* __restrict__ pdts,
    int b, int t, float* sv, float* red)
{
    int tid = threadIdx.x;
    float pdl = pdls[b], pdt = pdts[b], sc = scales[b];
    for (int r = tid; r < 512; r += 256) {
        const float* bx = boxes + (size_t)(b * 512 + r) * 4;
        float o0 = (bx[0] - pdl) / sc;
        float o1 = (bx[1] - pdt) / sc;
        float o2 = (bx[2] - pdl) / sc;
        float o3 = (bx[3] - pdt) / sc;
        sv[r]  = (t == 0) ? (o1 + o3) * 0.5f : (o0 + o2) * 0.5f;
        red[r] = (t == 0) ? fmaxf(o1, o3)    : fmaxf(o0, o2);
    }
    __syncthreads();
    red[tid] = fmaxf(red[tid], red[tid + 256]);
    __syncthreads();
    for (int s = 128; s > 0; s >>= 1) {
        if (tid < s) red[tid] = fmaxf(red[tid], red[tid + s]);
        __syncthreads();
    }
    float tbv = red[0];
    __syncthreads();
    return tbv;
}

#define QBITS(e, QB)                                                   \
    {                                                                  \
        int i_ = (e) / 511; int jj_ = (e) - i_ * 511;                  \
        int j_ = jj_ + (jj_ >= i_ ? 1 : 0);                            \
        float diff_ = sv[i_] - sv[j_];                                 \
        float u_ = (diff_ * 5.0f) / tbv;                               \
        float q_ = u_ * u_;                                            \
        QB = __float_as_uint(q_);                                      \
    }

// 12-bit hist pass (SHIFT selects bits; FILTER on/off via pfx).
__device__ __forceinline__ void hist12_256(
    const float* __restrict__ boxes, const float* __restrict__ scales,
    const float* __restrict__ pdls, const float* __restrict__ pdts,
    u32* __restrict__ gpart, int h, char* smem,
    int pass /*0=A no filter,1=B filter p12*/, const u32* __restrict__ meta)
{
    float* sv = (float*)smem; float* red = (float*)(smem + 2048);
    u32* lh = (u32*)(smem + 4096);
    const int sel = h >> 5, chunk = h & 31, b = sel >> 1, t = sel & 1;
    const int tid = threadIdx.x;
    for (int i = tid; i < 4096; i += 256) lh[i] = 0;
    const float tbv = sv_tb_256(boxes, scales, pdls, pdts, b, t, sv, red);
    const u32 p12 = pass ? meta[sel * MS + 0] : 0u;
    const int e1 = min((chunk + 1) * ECHUNK, NE);
    for (int e = chunk * ECHUNK + tid; e < e1; e += 256) {
        u32 qb; QBITS(e, qb);
        if (pass == 0) atomicAdd(&lh[qb >> 20], 1u);
        else if ((qb >> 20) == p12) atomicAdd(&lh[(qb >> 8) & 0xFFF], 1u);
    }
    __syncthreads();
    u32* G = gpart + ((size_t)sel * NCHUNK + chunk) * 4096;
    for (int i = tid; i < 4096; i += 256) G[i] = lh[i];
}

// scan of 4096 bins (256 thr, 16 bins/thread, same bin order as original).
// pass 0: threshold KEDGE -> meta[0,1]; pass 1: TH=meta[1] -> meta[6,7].
__device__ __forceinline__ void scan12_256(
    const u32* __restrict__ gpart, u32* __restrict__ meta, int sel,
    char* smem, int pass)
{
    u32* bins = (u32*)smem;
    u32* sc2  = (u32*)(smem + 16384);
    const int tid = threadIdx.x;
    const u32 TH = pass ? meta[sel * MS + 1] : (u32)KEDGE;
    for (int bb = tid; bb < 4096; bb += 256) {
        u32 s = 0;
        for (int c = 0; c < NCHUNK; ++c) s += gpart[((size_t)sel * NCHUNK + c) * 4096 + bb];
        bins[bb] = s;
    }
    __syncthreads();
    u32 part = 0;
#pragma unroll
    for (int j = 0; j < 16; ++j) part += bins[tid * 16 + j];
    sc2[tid] = part;
    __syncthreads();
    int src = 0;
    for (int st = 1; st < 256; st <<= 1) {
        sc2[(1 - src) * 256 + tid] = sc2[src * 256 + tid] + (tid >= st ? sc2[src * 256 + tid - st] : 0);
        __syncthreads(); src = 1 - src;
    }
    u32 inc = sc2[src * 256 + tid], exc = inc - part;
    if (exc < TH && TH <= inc) {
        u32 cum = exc;
        for (int j = 0; j < 16; ++j) {
            u32 c = bins[tid * 16 + j];
            if (cum + c >= TH) {
                if (pass == 0) {
                    meta[sel * MS + 0] = (u32)(tid * 16 + j);
                    meta[sel * MS + 1] = TH - cum;
                } else {
                    meta[sel * MS + 6] = (meta[sel * MS + 0] << 12) | (u32)(tid * 16 + j);
                    meta[sel * MS + 7] = TH - cum;
                }
                break;
            }
            cum += c;
        }
    }
}

// histC (low 8 bits among prefix24 matches), 256 thr.
__device__ __forceinline__ void histC_256(
    const float* __restrict__ boxes, const float* __restrict__ scales,
    const float* __restrict__ pdls, const float* __restrict__ pdts,
    const u32* __restrict__ meta, u32* __restrict__ gpart, int h, char* smem)
{
    float* sv = (float*)smem; float* red = (float*)(smem + 2048);
    u32* lh = (u32*)(smem + 4096);
    const int sel = h >> 5, chunk = h & 31, b = sel >> 1, t = sel & 1;
    const int tid = threadIdx.x;
    lh[tid] = 0;
    const float tbv = sv_tb_256(boxes, scales, pdls, pdts, b, t, sv, red);
    const u32 p24 = meta[sel * MS + 6];
    const int e1 = min((chunk + 1) * ECHUNK, NE);
    for (int e = chunk * ECHUNK + tid; e < e1; e += 256) {
        u32 qb; QBITS(e, qb);
        if ((qb >> 8) == p24) atomicAdd(&lh[qb & 0xFF], 1u);
    }
    __syncthreads();
    u32* G = gpart + ((size_t)sel * NCHUNK + chunk) * 256;
    G[tid] = lh[tid];
}

// ---------------------------------------------------------------------------
// shared GEMM body: C = act(A @ Bt^T + bias). 64x64 tile, 4 waves 2x2.
// gl_lds staging + LDS double-buffer + counted vmcnt(2) + raw s_barrier.
// aSp/bSp: 2 x 2048 f16 each (16KB total).
// ---------------------------------------------------------------------------
template <int ACT, typename OUTT>
__device__ __forceinline__ void gemm_body(
    const _Float16* __restrict__ A, const _Float16* __restrict__ Bt,
    const _Float16* __restrict__ zbuf, const float* __restrict__ bias,
    OUTT* __restrict__ C, int N, int K, int ldC, int n0, int m0,
    _Float16* aSp, _Float16* bSp)
{
    const int tid = threadIdx.x;
    const int wv = tid >> 6, ln = tid & 63;
    const int wm = wv & 1, wn = wv >> 1;
    const int lm = ln & 15, lq = ln >> 4;
    const int sr = tid >> 2, sq = tid & 3;

    const _Float16* asrc = A + (size_t)(m0 + sr) * K + sq * 8;
    const _Float16* bsrc = (n0 + sr < N) ? (Bt + (size_t)(n0 + sr) * K + sq * 8) : zbuf;

    f32x4 acc[2][2];
#pragma unroll
    for (int i = 0; i < 2; ++i)
#pragma unroll
        for (int j = 0; j < 2; ++j) acc[i][j] = (f32x4){0.f, 0.f, 0.f, 0.f};

    const int NT = K >> 5;
    GLD16(asrc, aSp + wv * 512);
    GLD16(bsrc, bSp + wv * 512);
#pragma unroll 1
    for (int it = 0; it < NT; ++it) {
        const int bi = it & 1;
        if (it + 1 < NT) {
            GLD16(asrc + (it + 1) * 32, aSp + (bi ^ 1) * 2048 + wv * 512);
            GLD16(bsrc + (it + 1) * 32, bSp + (bi ^ 1) * 2048 + wv * 512);
            asm volatile("s_waitcnt vmcnt(2)" ::: "memory");
        } else {
            asm volatile("s_waitcnt vmcnt(0)" ::: "memory");
        }
        __builtin_amdgcn_s_barrier();
        f16x8 af[2], bf[2];
#pragma unroll
        for (int mt = 0; mt < 2; ++mt)
            af[mt] = *(const f16x8*)(aSp + bi * 2048 + (wm * 32 + mt * 16 + lm) * 32 + lq * 8);
#pragma unroll
        for (int nt = 0; nt < 2; ++nt)
            bf[nt] = *(const f16x8*)(bSp + bi * 2048 + (wn * 32 + nt * 16 + lm) * 32 + lq * 8);
#pragma unroll
        for (int mt = 0; mt < 2; ++mt)
#pragma unroll
            for (int nt = 0; nt < 2; ++nt)
                acc[mt][nt] = __builtin_amdgcn_mfma_f32_16x16x32_f16(af[mt], bf[nt], acc[mt][nt], 0, 0, 0);
        __builtin_amdgcn_sched_barrier(0);
        __builtin_amdgcn_s_barrier();
    }

#pragma unroll
    for (int mt = 0; mt < 2; ++mt) {
#pragma unroll
        for (int nt = 0; nt < 2; ++nt) {
            int col = n0 + wn * 32 + nt * 16 + lm;
            if (col >= N) continue;
            float bs = bias ? bias[col] : 0.f;
#pragma unroll
            for (int r = 0; r < 4; ++r) {
                int row = m0 + wm * 32 + mt * 16 + lq * 4 + r;
                float v = acc[mt][nt][r] + bs;
                if (ACT == 1) v = fmaxf(v, 0.f);
                if (ACT == 2) v = (v >= 0.f) ? v : 0.01f * v;
                C[(size_t)row * ldC + col] = (OUTT)v;
            }
        }
    }
}

// ---------------------------------------------------------------------------
// F1: conv (blocks 0..767, round-3 measured-optimum structure) || histA
// (blocks 768..1023 @256thr). Edge chain is boxes-only dependent, so its
// VALU work hides in conv's measured ~60k cyc/CU stall (m114 co-schedule).
// ---------------------------------------------------------------------------
#define STAGE(cc)                                                            \
    {                                                                        \
        _Pragma("unroll")                                                    \
        for (int it = 0; it < 5; ++it) {                                     \
            if (it * 256 + wv * 64 < 1152)                                   \
                GLD16(wsrc[it] + (cc), &wS[(it * 256 + wv * 64) * 8]);       \
        }                                                                    \
        _Pragma("unroll")                                                    \
        for (int it = 0; it < 8; ++it)                                       \
            GLD16(xsrc[it] + (cc), &xS[(it * 256 + wv * 64) * 8]);           \
    }

#define LDB(BUF, R)                                                          \
    {                                                                        \
        _Pragma("unroll")                                                    \
        for (int u = 0; u < 9; ++u) {                                        \
            int nt_ = u / 3, dx_ = u % 3;                                    \
            BUF[u] = *(const f16x8*)&xS[(((R) * 4 + q) * 50 + nt_ * 16 + n + dx_) * 8]; \
        }                                                                    \
    }

#define DOTAP(TAP, BLO, BHI)                                                 \
    {                                                                        \
        _Pragma("unroll")                                                    \
        for (int dx_ = 0; dx_ < 3; ++dx_) {                                  \
            f16x8 a0 = *(const f16x8*)&wS[(((TAP) + dx_) * 128 + q * 32 + n) * 8];      \
            f16x8 a1 = *(const f16x8*)&wS[(((TAP) + dx_) * 128 + q * 32 + 16 + n) * 8]; \
            _Pragma("unroll")                                                \
            for (int nt_ = 0; nt_ < 3; ++nt_) {                              \
                f16x8 blo = BLO[nt_ * 3 + dx_];                              \
                f16x8 bhi = BHI[nt_ * 3 + dx_];                              \
                acc[0][0][nt_] = __builtin_amdgcn_mfma_f32_16x16x32_f16(a0, blo, acc[0][0][nt_], 0, 0, 0); \
                acc[1][0][nt_] = __builtin_amdgcn_mfma_f32_16x16x32_f16(a1, blo, acc[1][0][nt_], 0, 0, 0); \
                acc[0][1][nt_] = __builtin_amdgcn_mfma_f32_16x16x32_f16(a0, bhi, acc[0][1][nt_], 0, 0, 0); \
                acc[1][1][nt_] = __builtin_amdgcn_mfma_f32_16x16x32_f16(a1, bhi, acc[1][1][nt_], 0, 0, 0); \
            }                                                                \
        }                                                                    \
    }

__global__ __launch_bounds__(256, 3) void conv_histA_kernel(
    const _Float16* __restrict__ xf, const _Float16* __restrict__ wf,
    const _Float16* __restrict__ zbuf, float* __restrict__ pbuf,
    const float* __restrict__ boxes, const float* __restrict__ scales,
    const float* __restrict__ pdls, const float* __restrict__ pdts,
    u32* __restrict__ gpartA)
{
    __shared__ __attribute__((aligned(16))) char smem[51200];
    const int bid = blockIdx.x;
    const int tid = threadIdx.x;
    if (bid >= 768) {
        hist12_256(boxes, scales, pdls, pdts, gpartA, bid - 768, smem, 0, nullptr);
        return;
    }
    _Float16* wS = (_Float16*)smem;            // 18432 B
    _Float16* xS = (_Float16*)(smem + 18432);  // 32768 B
    // XCD-chunked swizzle: physical p -> XCD p%8; logical L consecutive per XCD
    const int p = bid;
    const int L = (p & 7) * 96 + (p >> 3);
    const int og = L & 7;
    const int t  = L >> 3;
    const int xt = t % 6;
    const int bz = t / 6;
    const int y0 = xt * 8;
    const int b  = bz >> 2, ks = bz & 3;
    const int wv = tid >> 6;
    const int ln = tid & 63;
    const int n  = ln & 15;
    const int q  = ln >> 4;

    f32x4 acc[2][2][3];
#pragma unroll
    for (int mt = 0; mt < 2; ++mt)
#pragma unroll
        for (int rr = 0; rr < 2; ++rr)
#pragma unroll
            for (int nt = 0; nt < 3; ++nt) acc[mt][rr][nt] = (f32x4){0.f, 0.f, 0.f, 0.f};

    const _Float16* wsrc[5];
    const _Float16* xsrc[8];
#pragma unroll
    for (int it = 0; it < 5; ++it) {
        int g = it * 256 + tid;
        int gg = (g < 1152) ? g : 0;
        int tap = gg >> 7, r = gg & 127, qq = r >> 5, oc = r & 31;
        wsrc[it] = wf + (size_t)(((og * 32 + oc) * 9 + tap) * 1024 + qq * 8);
    }
#pragma unroll
    for (int it = 0; it < 8; ++it) {
        int g = it * 256 + tid;
        int row = g / 200, r2 = g - row * 200;
        int qq = r2 / 50, c = r2 - qq * 50;
        int gy = y0 + row - 1, gx = c - 1;
        bool inb = (g < 2000) && ((unsigned)gy < 48u) && ((unsigned)gx < 48u);
        xsrc[it] = inb ? (xf + (size_t)(((b * 48 + gy) * 48 + gx) * 1024 + qq * 8)) : zbuf;
    }

    const int c0 = ks * 256;
    const int rbase = 2 * wv;

    STAGE(c0);

#pragma unroll 1
    for (int ci = 0; ci < 8; ++ci) {
        asm volatile("s_waitcnt vmcnt(0)" ::: "memory");
        __syncthreads();

        __builtin_amdgcn_s_setprio(1);
        f16x8 bA[9], bB[9];
        LDB(bA, rbase + 0);
        LDB(bB, rbase + 1);
        DOTAP(0, bA, bB);
        LDB(bA, rbase + 2);
        DOTAP(3, bB, bA);
        LDB(bB, rbase + 3);
        DOTAP(6, bA, bB);
        __builtin_amdgcn_s_setprio(0);
        __syncthreads();
        if (ci < 7) STAGE(c0 + (ci + 1) * 32);
    }

#pragma unroll
    for (int rr = 0; rr < 2; ++rr) {
        const int y = y0 + 2 * wv + rr;
#pragma unroll
        for (int mt = 0; mt < 2; ++mt) {
#pragma unroll
            for (int nt = 0; nt < 3; ++nt) {
                int x = nt * 16 + n;
                *(f32x4*)(pbuf + (size_t)ks * PSLICE +
                          ((size_t)(b * 48 + y) * 48 + x) * 256 + og * 32 + mt * 16 + q * 4) = acc[mt][rr][nt];
            }
        }
    }
}

// ---------------------------------------------------------------------------
// F2: conv_sum (blocks 0..2303) || scanA (2304..2311).
// ---------------------------------------------------------------------------
__global__ __launch_bounds__(256) void sum_scanA_kernel(
    const float* __restrict__ pbuf, const float* __restrict__ bd,
    _Float16* __restrict__ dec, const u32* __restrict__ gpartA,
    u32* __restrict__ meta)
{
    __shared__ __attribute__((aligned(16))) char smem[18432];
    const int bid = blockIdx.x;
    if (bid >= 2304) { scan12_256(gpartA, meta, bid - 2304, smem, 0); return; }
    size_t idx = (size_t)bid * 256 + threadIdx.x;
    size_t e = idx * 4;
    int och = (int)(e & 255);
    f32x4 s0 = *(const f32x4*)(pbuf + e);
    f32x4 s1 = *(const f32x4*)(pbuf + (size_t)PSLICE + e);
    f32x4 s2 = *(const f32x4*)(pbuf + (size_t)2 * PSLICE + e);
    f32x4 s3 = *(const f32x4*)(pbuf + (size_t)3 * PSLICE + e);
    float4 b4 = *(const float4*)(bd + och);
    f16x4 v;
    v.x = (_Float16)fmaxf(s0[0] + s1[0] + s2[0] + s3[0] + b4.x, 0.f);
    v.y = (_Float16)fmaxf(s0[1] + s1[1] + s2[1] + s3[1] + b4.y, 0.f);
    v.z = (_Float16)fmaxf(s0[2] + s1[2] + s2[2] + s3[2] + b4.z, 0.f);
    v.w = (_Float16)fmaxf(s0[3] + s1[3] + s2[3] + s3[3] + b4.w, 0.f);
    *(f16x4*)(dec + e) = v;
}

// ---------------------------------------------------------------------------
// F3: roi+box head (blocks 0..2047) || histB (2048..2303).
// ---------------------------------------------------------------------------
__global__ __launch_bounds__(256) void roi_histB_kernel(
    const _Float16* __restrict__ dec, const float* __restrict__ boxes,
    const float* __restrict__ Wb, const float* __restrict__ bb,
    _Float16* __restrict__ cnn, _Float16* __restrict__ fusion,
    const float* __restrict__ scales, const float* __restrict__ pdls,
    const float* __restrict__ pdts, const u32* __restrict__ meta,
    u32* __restrict__ gpartB)
{
    __shared__ __attribute__((aligned(16))) char smem[20480];
    const int nblk = blockIdx.x;
    if (nblk >= 2048) {
        hist12_256(boxes, scales, pdls, pdts, gpartB, nblk - 2048, smem, 1, meta);
        return;
    }
    int n = nblk; int c = threadIdx.x;
    int b = n >> 9;
    float x1 = boxes[n * 4 + 0], y1 = boxes[n * 4 + 1];
    float x2 = boxes[n * 4 + 2], y2 = boxes[n * 4 + 3];
    // ---- box head ----
    {
        float bf0 = ((x1 + x2) * 0.5f) / 48.f;
        float bf1 = ((y1 + y2) * 0.5f) / 48.f;
        float bf2 = (x2 - x1) / 48.f;
        float bf3 = (y2 - y1) / 48.f;
        float acc = bb[c];
        acc += bf0 * Wb[0 * 256 + c];
        acc += bf1 * Wb[1 * 256 + c];
        acc += bf2 * Wb[2 * 256 + c];
        acc += bf3 * Wb[3 * 256 + c];
        fusion[(size_t)n * 768 + c] = (_Float16)fmaxf(acc, 0.f);
    }
    // ---- roi ----
    float bw = (x2 - x1) * 0.5f, bh = (y2 - y1) * 0.5f;
    float sxv[2] = { x1 + 0.5f * bw, x1 + 1.5f * bw };
    float syv[2] = { y1 + 0.5f * bh, y1 + 1.5f * bh };
    float px[4] = { sxv[0], sxv[1], sxv[0], sxv[1] };
    float py[4] = { syv[0], syv[0], syv[1], syv[1] };
    const _Float16* f = dec + (size_t)b * 2304 * 256;
    f16x4 o4;
    float res[4];
#pragma unroll
    for (int p = 0; p < 4; ++p) {
        float yy = fminf(fmaxf(py[p], 0.f), 47.f);
        float xx = fminf(fmaxf(px[p], 0.f), 47.f);
        int y0 = (int)floorf(yy), x0 = (int)floorf(xx);
        int y1i = min(y0 + 1, 47), x1i = min(x0 + 1, 47);
        float wy = yy - (float)y0, wx = xx - (float)x0;
        float f00 = (float)f[(size_t)(y0 * 48 + x0) * 256 + c];
        float f01 = (float)f[(size_t)(y0 * 48 + x1i) * 256 + c];
        float f10 = (float)f[(size_t)(y1i * 48 + x0) * 256 + c];
        float f11 = (float)f[(size_t)(y1i * 48 + x1i) * 256 + c];
        res[p] = f00 * (1.f - wy) * (1.f - wx) + f01 * (1.f - wy) * wx
               + f10 * wy * (1.f - wx) + f11 * wy * wx;
    }
    o4.x = (_Float16)res[0]; o4.y = (_Float16)res[1];
    o4.z = (_Float16)res[2]; o4.w = (_Float16)res[3];
    *(f16x4*)(cnn + (size_t)n * 1024 + c * 4) = o4;
}

// ---------------------------------------------------------------------------
// F4: gemm cnn@WcT -> fusion[:,256:768] (blocks 0..255) || scanB (256..263).
// ---------------------------------------------------------------------------
__global__ __launch_bounds__(256) void gemmcnn_scanB_kernel(
    const _Float16* __restrict__ cnn, const _Float16* __restrict__ WcT,
    const _Float16* __restrict__ zbuf, const float* __restrict__ b_cnn,
    _Float16* __restrict__ fusionC, const u32* __restrict__ gpartB,
    u32* __restrict__ meta)
{
    __shared__ __attribute__((aligned(16))) char smem[18432];
    const int bid = blockIdx.x;
    if (bid >= 256) { scan12_256(gpartB, meta, bid - 256, smem, 1); return; }
    const int n0 = (bid & 7) * 64, m0 = (bid >> 3) * 64;
    gemm_body<1, _Float16>(cnn, WcT, zbuf, b_cnn, fusionC, 512, 1024, 768, n0, m0,
                           (_Float16*)smem, (_Float16*)(smem + 8192));
}

// ---------------------------------------------------------------------------
// F5: dual gemm fusion@Wg{row,col} -> xw (blocks 0..511) || histC (512..767).
// ---------------------------------------------------------------------------
__global__ __launch_bounds__(256) void gemmz_histC_kernel(
    const _Float16* __restrict__ fusion,
    const _Float16* __restrict__ WgrT, const _Float16* __restrict__ WgcT,
    const _Float16* __restrict__ zbuf,
    float* __restrict__ C0, float* __restrict__ C1,
    const float* __restrict__ boxes, const float* __restrict__ scales,
    const float* __restrict__ pdls, const float* __restrict__ pdts,
    const u32* __restrict__ meta, u32* __restrict__ gpartC)
{
    __shared__ __attribute__((aligned(16))) char smem[16384];
    const int bid = blockIdx.x;
    if (bid >= 512) {
        histC_256(boxes, scales, pdls, pdts, meta, gpartC, bid - 512, smem);
        return;
    }
    const int z = bid >> 8, rem = bid & 255;
    const int n0 = (rem & 7) * 64, m0 = (rem >> 3) * 64;
    gemm_body<0, float>(fusion, z ? WgcT : WgrT, zbuf, nullptr, z ? C1 : C0,
                        512, 768, 512, n0, m0,
                        (_Float16*)smem, (_Float16*)(smem + 8192));
}

// ---------------------------------------------------------------------------
// dual classifier-head kernel (leaky 0.01), grid (4,32,2).
// ---------------------------------------------------------------------------
__global__ __launch_bounds__(256) void gemm16h_kernel(
    const _Float16* __restrict__ A0, const _Float16* __restrict__ A1,
    const _Float16* __restrict__ Bt0, const _Float16* __restrict__ Bt1,
    const _Float16* __restrict__ zbuf,
    const float* __restrict__ bias0, const float* __restrict__ bias1,
    float* __restrict__ C0, float* __restrict__ C1,
    int M, int N0, int N1, int K)
{
    __shared__ __attribute__((aligned(16))) char smem[16384];
    const int z = blockIdx.z;
    const int N = z ? N1 : N0;
    const int n0 = blockIdx.x * 64, m0 = blockIdx.y * 64;
    if (n0 >= N) return;
    gemm_body<2, float>(z ? A1 : A0, z ? Bt1 : Bt0, zbuf, z ? bias1 : bias0,
                        z ? C1 : C0, N, K, N, n0, m0,
                        (_Float16*)smem, (_Float16*)(smem + 8192));
}

// ---------------------------------------------------------------------------
// 1024-thread helpers for emit (unchanged).
// ---------------------------------------------------------------------------
__device__ __forceinline__ float compute_sv_tb(
    const float* __restrict__ boxes, const float* __restrict__ scales,
    const float* __restrict__ pdls, const float* __restrict__ pdts,
    int b, int t, float* sv, float* red)
{
    int tid = threadIdx.x;
    float pdl = pdls[b], pdt = pdts[b], sc = scales[b];
    if (tid < 512) {
        const float* bx = boxes + (size_t)(b * 512 + tid) * 4;
        float o0 = (bx[0] - pdl) / sc;
        float o1 = (bx[1] - pdt) / sc;
        float o2 = (bx[2] - pdl) / sc;
        float o3 = (bx[3] - pdt) / sc;
        sv[tid]  = (t == 0) ? (o1 + o3) * 0.5f : (o0 + o2) * 0.5f;
        red[tid] = (t == 0) ? fmaxf(o1, o3)    : fmaxf(o0, o2);
    }
    __syncthreads();
    for (int s = 256; s > 0; s >>= 1) {
        if (tid < s) red[tid] = fmaxf(red[tid], red[tid + s]);
        __syncthreads();
    }
    float tbv = red[0];
    __syncthreads();
    return tbv;
}

// scanC: exact q*, then binary-search the w*-tie q-interval [qlo,qhi].
__global__ __launch_bounds__(256) void scanC_kernel(
    const u32* __restrict__ gpart, u32* __restrict__ meta)
{
    const int sel = blockIdx.x, tid = threadIdx.x;
    const u32 TH = meta[sel * MS + 7];
    __shared__ u32 bins[256];
    __shared__ u32 sc[2][256];
    __shared__ u32 s_qstar;
    u32 s = 0;
    for (int c = 0; c < NCHUNK; ++c) s += gpart[((size_t)sel * NCHUNK + c) * 256 + tid];
    bins[tid] = s;
    sc[0][tid] = s;
    __syncthreads();
    int src = 0;
    for (int st = 1; st < 256; st <<= 1) {
        sc[1 - src][tid] = sc[src][tid] + (tid >= st ? sc[src][tid - st] : 0);
        __syncthreads(); src = 1 - src;
    }
    u32 inc = sc[src][tid], exc = inc - bins[tid];
    if (exc < TH && TH <= inc)
        s_qstar = (meta[sel * MS + 6] << 8) | (u32)tid;
    __syncthreads();
    if (tid == 0) {
        u32 prefix = s_qstar;
        float qstar = __uint_as_float(prefix);
        float wstar = (float)exp(-(double)qstar);
        u32 lo = 0, hi = prefix;              // smallest qb with exp(-q)==w*
        while (lo < hi) {
            u32 mid = (lo + hi) >> 1;
            float wm = (float)exp(-(double)__uint_as_float(mid));
            if (wm > wstar) lo = mid + 1; else hi = mid;
        }
        meta[sel * MS + 2] = lo;
        lo = prefix; hi = 0x7F800000u;        // largest qb with exp(-q)==w*
        while (lo < hi) {
            u32 mid = (lo + hi + 1) >> 1;
            float wm = (float)exp(-(double)__uint_as_float(mid));
            if (wm < wstar) hi = mid - 1; else lo = mid;
        }
        meta[sel * MS + 3] = lo;
        meta[sel * MS + 4] = __float_as_uint(wstar);
    }
}

// ---------------------------------------------------------------------------
// emit: two-pass block-aggregated slot reservation. 32 chunks x 8 sels.
// ---------------------------------------------------------------------------
__global__ __launch_bounds__(1024) void emit_kernel(
    const float* __restrict__ boxes, const float* __restrict__ scales,
    const float* __restrict__ pdls, const float* __restrict__ pdts,
    u32* __restrict__ meta, int* __restrict__ tiebuf, int* __restrict__ tiecnt,
    int* __restrict__ es, int* __restrict__ ed, float* __restrict__ ewt,
    int* __restrict__ indeg, float* __restrict__ degw)
{
    __shared__ float sv[512]; __shared__ float red[512];
    __shared__ int s_wcnt, s_tcnt, s_wbase, s_tbase;
    const int sel = blockIdx.y, b = sel >> 1, t = sel & 1;
    const int tid = threadIdx.x;
    const float tbv = compute_sv_tb(boxes, scales, pdls, pdts, b, t, sv, red);
    const u32 qlo = meta[sel * MS + 2], qhi = meta[sel * MS + 3];
    const int base = t * 16384 + b * 4096;
    const int e0 = blockIdx.x * ECHUNK + tid;
    const int e1 = min((int)(blockIdx.x + 1) * ECHUNK, NE);
    if (tid == 0) { s_wcnt = 0; s_tcnt = 0; }
    __syncthreads();
    int myw = 0, myt = 0;
    for (int e = e0; e < e1; e += 1024) {
        u32 qb; QBITS(e, qb);
        if (qb < qlo) ++myw;
        else if (qb <= qhi) ++myt;
    }
    if (myw) atomicAdd(&s_wcnt, myw);
    if (myt) atomicAdd(&s_tcnt, myt);
    __syncthreads();
    if (tid == 0) {
        s_wbase = (s_wcnt > 0) ? (int)atomicAdd(&meta[sel * MS + 5], (u32)s_wcnt) : 0;
        s_tbase = (s_tcnt > 0) ? atomicAdd(&tiecnt[sel * TS], s_tcnt) : 0;
        s_wcnt = 0; s_tcnt = 0;
    }
    __syncthreads();
    for (int e = e0; e < e1; e += 1024) {
        u32 qb; QBITS(e, qb);
        if (qb < qlo) {
            int i = e / 511; int jj = e - i * 511; int j = jj + (jj >= i ? 1 : 0);
            float wval = (float)exp(-(double)__uint_as_float(qb));
            int slot = s_wbase + atomicAdd(&s_wcnt, 1);
            es[base + slot] = b * 512 + i;
            ed[base + slot] = b * 512 + j;
            ewt[base + slot] = wval;
            atomicAdd(&indeg[t * 2048 + b * 512 + j], 1);
            atomicAdd(&degw[t * 2048 + b * 512 + j], wval);
        } else if (qb <= qhi) {
            int p = s_tbase + atomicAdd(&s_tcnt, 1);
            if (p < TIECAP) tiebuf[sel * TIECAP + p] = e;
        }
    }
}

// ---------------------------------------------------------------------------
// tie resolution + indeg scan + dis + CSR fill. grid 2 (t), block 1024.
// ---------------------------------------------------------------------------
__global__ __launch_bounds__(1024) void tie_scan_fill_kernel(
    u32* __restrict__ meta, const int* __restrict__ tiebuf, const int* __restrict__ tiecnt,
    int* __restrict__ es, int* __restrict__ ed, float* __restrict__ ewt,
    int* __restrict__ indeg, float* __restrict__ degw,
    int* __restrict__ offs, float* __restrict__ dis, int* __restrict__ csr)
{
    __shared__ int bufA[2048], bufB[2048];
    __shared__ int fill_l[2048];
    const int t = blockIdx.x, tid = threadIdx.x;
    for (int b = 0; b < 4; ++b) {
        int sel = b * 2 + t;
        int m = min(tiecnt[sel * TS], TIECAP);
        int r = KEDGE - (int)meta[sel * MS + 5];
        float wt = __uint_as_float(meta[sel * MS + 4]);
        int base = t * 16384 + b * 4096;
        for (int k = tid; k < m; k += 1024) {
            int e = tiebuf[sel * TIECAP + k];
            int rank = 0;
            for (int l = 0; l < m; ++l) rank += (tiebuf[sel * TIECAP + l] < e) ? 1 : 0;
            if (rank < r) {
                int i = e / 511; int jj = e - i * 511; int j = jj + (jj >= i ? 1 : 0);
                int slot = (int)atomicAdd(&meta[sel * MS + 5], 1u);
                es[base + slot] = b * 512 + i;
                ed[base + slot] = b * 512 + j;
                ewt[base + slot] = wt;
                atomicAdd(&indeg[t * 2048 + b * 512 + j], 1);
                atomicAdd(&degw[t * 2048 + b * 512 + j], wt);
            }
        }
    }
    __threadfence();
    __syncthreads();
    // exclusive scan of indeg -> offs (global + LDS copy in bufA)
    bufA[tid] = indeg[t * 2048 + tid];
    bufA[tid + 1024] = indeg[t * 2048 + tid + 1024];
    fill_l[tid] = 0; fill_l[tid + 1024] = 0;
    __syncthreads();
    int* src = bufA; int* dst = bufB;
    for (int st = 1; st < 2048; st <<= 1) {
        dst[tid] = src[tid] + (tid >= st ? src[tid - st] : 0);
        int k1 = tid + 1024;
        dst[k1] = src[k1] + (k1 >= st ? src[k1 - st] : 0);
        __syncthreads();
        int* tmp = src; src = dst; dst = tmp;
    }
    int off0 = (tid == 0) ? 0 : src[tid - 1];
    int off1 = src[tid + 1023];
    __syncthreads();
    // write offs to LDS (reuse dst buffer) + global
    dst[tid] = off0; dst[tid + 1024] = off1;
    offs[t * 2048 + tid] = off0;
    offs[t * 2048 + tid + 1024] = off1;
    dis[t * 2048 + tid] = 1.0f / sqrtf(1.0f + degw[t * 2048 + tid]);
    dis[t * 2048 + tid + 1024] = 1.0f / sqrtf(1.0f + degw[t * 2048 + tid + 1024]);
    __syncthreads();
    // CSR fill over this t's 16384 edges
    for (int e = tid; e < 16384; e += 1024) {
        int dl = ed[t * 16384 + e] & 2047;
        int pos = dst[dl] + atomicAdd(&fill_l[dl], 1);
        csr[t * 16384 + pos] = e;
    }
}

// E7: GCN aggregate -> feats f16
__global__ __launch_bounds__(256) void gcn_agg_kernel(
    const float* __restrict__ xw_row, const float* __restrict__ xw_col,
    const float* __restrict__ b_row, const float* __restrict__ b_col,
    const int* __restrict__ es, const float* __restrict__ ew,
    const int* __restrict__ csr, const int* __restrict__ offs,
    const int* __restrict__ indeg, const float* __restrict__ dis,
    _Float16* __restrict__ feat_row, _Float16* __restrict__ feat_col)
{
    int d = blockIdx.x; int t = blockIdx.y;
    const float* xw = t ? xw_col : xw_row;
    const float* bg = t ? b_col : b_row;
    _Float16* out = t ? feat_col : feat_row;
    int f0 = threadIdx.x, f1 = threadIdx.x + 256;
    float dd = dis[t * 2048 + d];
    float a0 = dd * dd * xw[(size_t)d * 512 + f0];
    float a1 = dd * dd * xw[(size_t)d * 512 + f1];
    int st = offs[t * 2048 + d], cnt = indeg[t * 2048 + d];
    for (int k = 0; k < cnt; ++k) {
        int e = csr[t * 16384 + st + k];
        int s = es[t * 16384 + e];
        float w = ew[t * 16384 + e];
        float coef = dis[t * 2048 + s] * w * dd;
        a0 += coef * xw[(size_t)s * 512 + f0];
        a1 += coef * xw[(size_t)s * 512 + f1];
    }
    a0 += bg[f0]; a1 += bg[f1];
    out[(size_t)d * 512 + f0] = (_Float16)fmaxf(a0, 0.f);
    out[(size_t)d * 512 + f1] = (_Float16)fmaxf(a1, 0.f);
}

// ---------------------------------------------------------------------------
extern "C" void kernel_launch(void* const* d_in, const int* in_sizes, int n_in,
                              void* d_out, int out_size, void* d_ws, size_t ws_size,
                              hipStream_t stream)
{
    const float* x      = (const float*)d_in[0];
    const float* boxes  = (const float*)d_in[1];
    const float* scales = (const float*)d_in[2];
    const float* pdls   = (const float*)d_in[3];
    const float* pdts   = (const float*)d_in[4];
    const float* W_dec  = (const float*)d_in[5];
    const float* b_dec  = (const float*)d_in[6];
    const float* W_box  = (const float*)d_in[7];
    const float* b_box  = (const float*)d_in[8];
    const float* W_cnn  = (const float*)d_in[9];
    const float* b_cnn  = (const float*)d_in[10];
    const float* W_grow = (const float*)d_in[11];
    const float* b_grow = (const float*)d_in[12];
    const float* W_gcol = (const float*)d_in[13];
    const float* b_gcol = (const float*)d_in[14];
    const float* W_rcls = (const float*)d_in[15];
    const float* b_rcls = (const float*)d_in[16];
    const float* W_ccls = (const float*)d_in[17];
    const float* b_ccls = (const float*)d_in[18];

    char* ws = (char*)d_ws;
    size_t off = 0;
    auto alloc = [&](size_t bytes) -> void* {
        void* p = ws + off;
        off = (off + bytes + 255) & ~(size_t)255;
        return p;
    };
    _Float16* xf16   = (_Float16*)alloc((size_t)4 * 2304 * 1024 * 2);  // NHWC in
    _Float16* wf16   = (_Float16*)alloc((size_t)256 * 9216 * 2);       // [o][tap][ch]
    _Float16* dec    = (_Float16*)alloc((size_t)4 * 2304 * 256 * 2);   // NHWC
    float*    pbuf   = (float*)   alloc((size_t)4 * PSLICE * 4);       // split-K(4) partials
    _Float16* cnn    = (_Float16*)alloc((size_t)2048 * 1024 * 2);
    _Float16* fusion = (_Float16*)alloc((size_t)2048 * 768 * 2);
    _Float16* WcT    = (_Float16*)alloc((size_t)512 * 1024 * 2);
    _Float16* WgrT   = (_Float16*)alloc((size_t)512 * 768 * 2);
    _Float16* WgcT   = (_Float16*)alloc((size_t)512 * 768 * 2);
    _Float16* WrT    = (_Float16*)alloc((size_t)228 * 512 * 2);
    _Float16* WccT   = (_Float16*)alloc((size_t)116 * 512 * 2);
    float* xw        = (float*)alloc((size_t)2097152 * 4);             // xw_row|xw_col
    _Float16* feats  = (_Float16*)alloc((size_t)2 * 2048 * 512 * 2);   // row|col
    int*  es     = (int*)  alloc((size_t)2 * 16384 * 4);
    int*  ed     = (int*)  alloc((size_t)2 * 16384 * 4);
    float* ewt   = (float*)alloc((size_t)2 * 16384 * 4);
    int*  offsA  = (int*)  alloc((size_t)4096 * 4);
    float* dis   = (float*)alloc((size_t)4096 * 4);
    int*  csr    = (int*)  alloc((size_t)2 * 16384 * 4);
    int*  tiebuf = (int*)  alloc((size_t)8 * TIECAP * 4);
    u32*  gpartA = (u32*)  alloc((size_t)8 * NCHUNK * 4096 * 4);   // fully overwritten
    u32*  gpartB = (u32*)  alloc((size_t)8 * NCHUNK * 4096 * 4);
    u32*  gpartC = (u32*)  alloc((size_t)8 * NCHUNK * 256 * 4);
    // ---- zero zone (one hipMemsetAsync) ----
    size_t z0 = off;
    u32*  meta   = (u32*)  alloc((size_t)8 * MS * 4);
    int*  tiecnt = (int*)  alloc((size_t)8 * TS * 4);
    int*  indeg  = (int*)  alloc((size_t)4096 * 4);
    float* degw  = (float*)alloc((size_t)4096 * 4);
    _Float16* zbuf = (_Float16*)alloc((size_t)4096);   // zero pad for OOB gl_lds sources
    size_t z1 = off;

    float* out = (float*)d_out;

    hipMemsetAsync(ws + z0, 0, z1 - z0, stream);

    // fused prep: cvt_x (3072) + cvt_w (256) + cvt_t5 (1472)
    prep_kernel<<<4800, 256, 0, stream>>>(x, xf16, W_dec, wf16,
                                          W_cnn, WcT, W_grow, WgrT, W_gcol, WgcT,
                                          W_rcls, WrT, W_ccls, WccT);
    // F1: conv (768) || histA (256)
    conv_histA_kernel<<<1024, 256, 0, stream>>>(xf16, wf16, zbuf, pbuf,
                                                boxes, scales, pdls, pdts, gpartA);
    // F2: conv_sum (2304) || scanA (8)
    sum_scanA_kernel<<<2312, 256, 0, stream>>>(pbuf, b_dec, dec, gpartA, meta);
    // F3: roi+box (2048) || histB (256)
    roi_histB_kernel<<<2304, 256, 0, stream>>>(dec, boxes, W_box, b_box, cnn, fusion,
                                               scales, pdls, pdts, meta, gpartB);
    // F4: gemm cnn (256) || scanB (8)
    gemmcnn_scanB_kernel<<<264, 256, 0, stream>>>(cnn, WcT, zbuf, b_cnn, fusion + 256,
                                                  gpartB, meta);
    // F5: dual gemm xw (512) || histC (256)
    gemmz_histC_kernel<<<768, 256, 0, stream>>>(fusion, WgrT, WgcT, zbuf,
                                                xw, xw + 1048576,
                                                boxes, scales, pdls, pdts, meta, gpartC);
    scanC_kernel<<<8, 256, 0, stream>>>(gpartC, meta);
    emit_kernel<<<dim3(NCHUNK, 8), 1024, 0, stream>>>(boxes, scales, pdls, pdts, meta,
                                                      tiebuf, tiecnt, es, ed, ewt, indeg, degw);
    tie_scan_fill_kernel<<<2, 1024, 0, stream>>>(meta, tiebuf, tiecnt, es, ed, ewt,
                                                 indeg, degw, offsA, dis, csr);
    gcn_agg_kernel<<<dim3(2048, 2), 256, 0, stream>>>(xw, xw + 1048576, b_grow, b_gcol,
                                                      es, ewt, csr, offsA, indeg, dis,
                                                      feats, feats + (size_t)2048 * 512);
    // both classifier heads (leaky 0.01) in one dual launch -> fp32 out
    gemm16h_kernel<<<dim3(4, 32, 2), 256, 0, stream>>>(feats, feats + (size_t)2048 * 512,
                                                       WrT, WccT, zbuf, b_rcls, b_ccls,
                                                       out, out + (size_t)2048 * 228,
                                                       2048, 228, 116, 512);
}

// Round 10
// 330.817 us; speedup vs baseline: 1.2417x; 1.2417x over previous
//
#include <hip/hip_runtime.h>
#include <cstdint>
#include <math.h>

typedef unsigned int u32;
typedef unsigned long long u64;
typedef unsigned short ushort;

typedef __attribute__((ext_vector_type(8))) _Float16 f16x8;
typedef __attribute__((ext_vector_type(4))) _Float16 f16x4;
typedef __attribute__((ext_vector_type(4))) float f32x4;

#define NB    4
#define BnN   2048
#define NE    261632      // 512*511 ordered pairs per batch
#define NCHUNK 32
#define ECHUNK 8176       // NE/32 exactly
#define KEDGE 4096
#define TIECAP 2048
#define PSLICE 2359296    // 4*2304*256 elements per K-slice partial
#define MS    64          // meta stride (u32) per sel -> 256B, own cache lines
#define TS    64          // tiecnt stride (int) per sel

#define GLD16(gsrc, ldst)                                                    \
    __builtin_amdgcn_global_load_lds(                                        \
        (const __attribute__((address_space(1))) void*)(gsrc),               \
        (__attribute__((address_space(3))) void*)(ldst), 16, 0, 0)

// meta[sel*MS+i]: 0:p12  1:need1  2:qlo  3:qhi  4:wstar  5:emitcnt  6:prefix24  7:need2
// ---------------------------------------------------------------------------
// prep: fused cvt_x (3072 blocks) + cvt_w (256) + cvt_t5 (1472). One launch.
// ---------------------------------------------------------------------------
__global__ __launch_bounds__(256) void prep_kernel(
    const float* __restrict__ in, _Float16* __restrict__ xf,
    const float* __restrict__ W, _Float16* __restrict__ wf,
    const float* __restrict__ Wc,  _Float16* __restrict__ WcT,
    const float* __restrict__ Wgr, _Float16* __restrict__ WgrT,
    const float* __restrict__ Wgc, _Float16* __restrict__ WgcT,
    const float* __restrict__ Wr,  _Float16* __restrict__ WrT,
    const float* __restrict__ Wcc, _Float16* __restrict__ WccT)
{
    __shared__ _Float16 sh[9216];
    const int bid = blockIdx.x;
    const int tid = threadIdx.x;
    if (bid < 3072) {
        // ---- cvt_x: NCHW fp32 -> NHWC f16 ----
        _Float16 (*shx)[49] = (_Float16(*)[49])sh;
        int cg = bid & 15, rem = bid >> 4;
        int y = rem % 48, b = rem / 48;
        for (int i = tid; i < 64 * 48; i += 256) {
            int cl = i / 48, x = i - cl * 48;
            shx[cl][x] = (_Float16)in[(((size_t)b * 1024 + cg * 64 + cl) * 48 + y) * 48 + x];
        }
        __syncthreads();
        for (int i = tid; i < 64 * 48; i += 256) {
            int x = i / 64, cl = i - x * 64;
            xf[((size_t)(b * 48 + y) * 48 + x) * 1024 + cg * 64 + cl] = shx[cl][x];
        }
    } else if (bid < 3328) {
        // ---- cvt_w: [o][ch][3][3] fp32 -> [o][tap][ch] f16 ----
        int o = bid - 3072;
        for (int g = tid; g < 9216; g += 256)
            sh[g] = (_Float16)W[(size_t)o * 9216 + g];     // g = ch*9+tap
        __syncthreads();
        for (int g = tid; g < 9216; g += 256) {
            int tap = g >> 10, ch = g & 1023;
            wf[(size_t)o * 9216 + g] = sh[ch * 9 + tap];
        }
    } else {
        // ---- cvt_t5: 5 weight matrices fp32 [K][N] -> f16 [N][K] ----
        _Float16 (*sht)[33] = (_Float16(*)[33])sh;
        int b2 = bid - 3328;
        const float* inm; _Float16* outm; int K, N, tx0, ty0, ntx;
        if (b2 < 512)       { inm = Wc;  outm = WcT;  K = 1024; N = 512; ntx = 16; b2 -= 0;    }
        else if (b2 < 896)  { inm = Wgr; outm = WgrT; K = 768;  N = 512; ntx = 16; b2 -= 512;  }
        else if (b2 < 1280) { inm = Wgc; outm = WgcT; K = 768;  N = 512; ntx = 16; b2 -= 896;  }
        else if (b2 < 1408) { inm = Wr;  outm = WrT;  K = 512;  N = 228; ntx = 8;  b2 -= 1280; }
        else                { inm = Wcc; outm = WccT; K = 512;  N = 116; ntx = 4;  b2 -= 1408; }
        tx0 = (b2 % ntx) * 32;   // n0
        ty0 = (b2 / ntx) * 32;   // k0
        int tx = tid & 31, ty = tid >> 5;
#pragma unroll
        for (int i = 0; i < 4; ++i) {
            int k = ty0 + ty + i * 8, n = tx0 + tx;
            sht[ty + i * 8][tx] = (k < K && n < N) ? (_Float16)inm[(size_t)k * N + n] : (_Float16)0.f;
        }
        __syncthreads();
#pragma unroll
        for (int i = 0; i < 4; ++i) {
            int n = tx0 + ty + i * 8, k = ty0 + tx;
            if (n < N && k < K) outm[(size_t)n * K + k] = sht[tx][ty + i * 8];
        }
    }
}

// ---------------------------------------------------------------------------
// 256-thread edge building blocks (bit-identical math to 1024-thr originals).
// Used only for HIST passes fused under MFMA kernels. Scans stay 1024-thr
// standalone (round-9 lesson: 256-thr scans = 4x latency chain on 8 blocks
// -> 60us serial tail).
// ---------------------------------------------------------------------------
__device__ __forceinline__ float sv_tb_256(
    const float* __restrict__ boxes, const float* __restrict__ scales,
    const float* __restrict__ pdls, const float* __restrict__ pdts,
    int b, int t, float* sv, float* red)
{
    int tid = threadIdx.x;
    float pdl = pdls[b], pdt = pdts[b], sc = scales[b];
    for (int r = tid; r < 512; r += 256) {
        const float* bx = boxes + (size_t)(b * 512 + r) * 4;
        float o0 = (bx[0] - pdl) / sc;
        float o1 = (bx[1] - pdt) / sc;
        float o2 = (bx[2] - pdl) / sc;
        float o3 = (bx[3] - pdt) / sc;
        sv[r]  = (t == 0) ? (o1 + o3) * 0.5f : (o0 + o2) * 0.5f;
        red[r] = (t == 0) ? fmaxf(o1, o3)    : fmaxf(o0, o2);
    }
    __syncthreads();
    red[tid] = fmaxf(red[tid], red[tid + 256]);
    __syncthreads();
    for (int s = 128; s > 0; s >>= 1) {
        if (tid < s) red[tid] = fmaxf(red[tid], red[tid + s]);
        __syncthreads();
    }
    float tbv = red[0];
    __syncthreads();
    return tbv;
}

#define QBITS(e, QB)                                                   \
    {                                                                  \
        int i_ = (e) / 511; int jj_ = (e) - i_ * 511;                  \
        int j_ = jj_ + (jj_ >= i_ ? 1 : 0);                            \
        float diff_ = sv[i_] - sv[j_];                                 \
        float u_ = (diff_ * 5.0f) / tbv;                               \
        float q_ = u_ * u_;                                            \
        QB = __float_as_uint(q_);                                      \
    }

// 12-bit hist pass. pass 0 = histA (no filter), pass 1 = histB (filter p12).
__device__ __forceinline__ void hist12_256(
    const float* __restrict__ boxes, const float* __restrict__ scales,
    const float* __restrict__ pdls, const float* __restrict__ pdts,
    u32* __restrict__ gpart, int h, char* smem,
    int pass, const u32* __restrict__ meta)
{
    float* sv = (float*)smem; float* red = (float*)(smem + 2048);
    u32* lh = (u32*)(smem + 4096);
    const int sel = h >> 5, chunk = h & 31, b = sel >> 1, t = sel & 1;
    const int tid = threadIdx.x;
    for (int i = tid; i < 4096; i += 256) lh[i] = 0;
    const float tbv = sv_tb_256(boxes, scales, pdls, pdts, b, t, sv, red);
    const u32 p12 = pass ? meta[sel * MS + 0] : 0u;
    const int e1 = min((chunk + 1) * ECHUNK, NE);
    for (int e = chunk * ECHUNK + tid; e < e1; e += 256) {
        u32 qb; QBITS(e, qb);
        if (pass == 0) atomicAdd(&lh[qb >> 20], 1u);
        else if ((qb >> 20) == p12) atomicAdd(&lh[(qb >> 8) & 0xFFF], 1u);
    }
    __syncthreads();
    u32* G = gpart + ((size_t)sel * NCHUNK + chunk) * 4096;
    for (int i = tid; i < 4096; i += 256) G[i] = lh[i];
}

// histC (low 8 bits among prefix24 matches), 256 thr.
__device__ __forceinline__ void histC_256(
    const float* __restrict__ boxes, const float* __restrict__ scales,
    const float* __restrict__ pdls, const float* __restrict__ pdts,
    const u32* __restrict__ meta, u32* __restrict__ gpart, int h, char* smem)
{
    float* sv = (float*)smem; float* red = (float*)(smem + 2048);
    u32* lh = (u32*)(smem + 4096);
    const int sel = h >> 5, chunk = h & 31, b = sel >> 1, t = sel & 1;
    const int tid = threadIdx.x;
    lh[tid] = 0;
    const float tbv = sv_tb_256(boxes, scales, pdls, pdts, b, t, sv, red);
    const u32 p24 = meta[sel * MS + 6];
    const int e1 = min((chunk + 1) * ECHUNK, NE);
    for (int e = chunk * ECHUNK + tid; e < e1; e += 256) {
        u32 qb; QBITS(e, qb);
        if ((qb >> 8) == p24) atomicAdd(&lh[qb & 0xFF], 1u);
    }
    __syncthreads();
    u32* G = gpart + ((size_t)sel * NCHUNK + chunk) * 256;
    G[tid] = lh[tid];
}

// ---------------------------------------------------------------------------
// shared GEMM body: C = act(A @ Bt^T + bias). 64x64 tile, 4 waves 2x2.
// gl_lds staging + LDS double-buffer + counted vmcnt(2) + raw s_barrier.
// ---------------------------------------------------------------------------
template <int ACT, typename OUTT>
__device__ __forceinline__ void gemm_body(
    const _Float16* __restrict__ A, const _Float16* __restrict__ Bt,
    const _Float16* __restrict__ zbuf, const float* __restrict__ bias,
    OUTT* __restrict__ C, int N, int K, int ldC, int n0, int m0,
    _Float16* aSp, _Float16* bSp)
{
    const int tid = threadIdx.x;
    const int wv = tid >> 6, ln = tid & 63;
    const int wm = wv & 1, wn = wv >> 1;
    const int lm = ln & 15, lq = ln >> 4;
    const int sr = tid >> 2, sq = tid & 3;

    const _Float16* asrc = A + (size_t)(m0 + sr) * K + sq * 8;
    const _Float16* bsrc = (n0 + sr < N) ? (Bt + (size_t)(n0 + sr) * K + sq * 8) : zbuf;

    f32x4 acc[2][2];
#pragma unroll
    for (int i = 0; i < 2; ++i)
#pragma unroll
        for (int j = 0; j < 2; ++j) acc[i][j] = (f32x4){0.f, 0.f, 0.f, 0.f};

    const int NT = K >> 5;
    GLD16(asrc, aSp + wv * 512);
    GLD16(bsrc, bSp + wv * 512);
#pragma unroll 1
    for (int it = 0; it < NT; ++it) {
        const int bi = it & 1;
        if (it + 1 < NT) {
            GLD16(asrc + (it + 1) * 32, aSp + (bi ^ 1) * 2048 + wv * 512);
            GLD16(bsrc + (it + 1) * 32, bSp + (bi ^ 1) * 2048 + wv * 512);
            asm volatile("s_waitcnt vmcnt(2)" ::: "memory");
        } else {
            asm volatile("s_waitcnt vmcnt(0)" ::: "memory");
        }
        __builtin_amdgcn_s_barrier();
        f16x8 af[2], bf[2];
#pragma unroll
        for (int mt = 0; mt < 2; ++mt)
            af[mt] = *(const f16x8*)(aSp + bi * 2048 + (wm * 32 + mt * 16 + lm) * 32 + lq * 8);
#pragma unroll
        for (int nt = 0; nt < 2; ++nt)
            bf[nt] = *(const f16x8*)(bSp + bi * 2048 + (wn * 32 + nt * 16 + lm) * 32 + lq * 8);
#pragma unroll
        for (int mt = 0; mt < 2; ++mt)
#pragma unroll
            for (int nt = 0; nt < 2; ++nt)
                acc[mt][nt] = __builtin_amdgcn_mfma_f32_16x16x32_f16(af[mt], bf[nt], acc[mt][nt], 0, 0, 0);
        __builtin_amdgcn_sched_barrier(0);
        __builtin_amdgcn_s_barrier();
    }

#pragma unroll
    for (int mt = 0; mt < 2; ++mt) {
#pragma unroll
        for (int nt = 0; nt < 2; ++nt) {
            int col = n0 + wn * 32 + nt * 16 + lm;
            if (col >= N) continue;
            float bs = bias ? bias[col] : 0.f;
#pragma unroll
            for (int r = 0; r < 4; ++r) {
                int row = m0 + wm * 32 + mt * 16 + lq * 4 + r;
                float v = acc[mt][nt][r] + bs;
                if (ACT == 1) v = fmaxf(v, 0.f);
                if (ACT == 2) v = (v >= 0.f) ? v : 0.01f * v;
                C[(size_t)row * ldC + col] = (OUTT)v;
            }
        }
    }
}

// ---------------------------------------------------------------------------
// F1: conv (blocks 0..767, round-3 measured-optimum) || histA (768..1023).
// Round-9 verified: F1 absent from top-5 -> histA hides under conv's stall.
// ---------------------------------------------------------------------------
#define STAGE(cc)                                                            \
    {                                                                        \
        _Pragma("unroll")                                                    \
        for (int it = 0; it < 5; ++it) {                                     \
            if (it * 256 + wv * 64 < 1152)                                   \
                GLD16(wsrc[it] + (cc), &wS[(it * 256 + wv * 64) * 8]);       \
        }                                                                    \
        _Pragma("unroll")                                                    \
        for (int it = 0; it < 8; ++it)                                       \
            GLD16(xsrc[it] + (cc), &xS[(it * 256 + wv * 64) * 8]);           \
    }

#define LDB(BUF, R)                                                          \
    {                                                                        \
        _Pragma("unroll")                                                    \
        for (int u = 0; u < 9; ++u) {                                        \
            int nt_ = u / 3, dx_ = u % 3;                                    \
            BUF[u] = *(const f16x8*)&xS[(((R) * 4 + q) * 50 + nt_ * 16 + n + dx_) * 8]; \
        }                                                                    \
    }

#define DOTAP(TAP, BLO, BHI)                                                 \
    {                                                                        \
        _Pragma("unroll")                                                    \
        for (int dx_ = 0; dx_ < 3; ++dx_) {                                  \
            f16x8 a0 = *(const f16x8*)&wS[(((TAP) + dx_) * 128 + q * 32 + n) * 8];      \
            f16x8 a1 = *(const f16x8*)&wS[(((TAP) + dx_) * 128 + q * 32 + 16 + n) * 8]; \
            _Pragma("unroll")                                                \
            for (int nt_ = 0; nt_ < 3; ++nt_) {                              \
                f16x8 blo = BLO[nt_ * 3 + dx_];                              \
                f16x8 bhi = BHI[nt_ * 3 + dx_];                              \
                acc[0][0][nt_] = __builtin_amdgcn_mfma_f32_16x16x32_f16(a0, blo, acc[0][0][nt_], 0, 0, 0); \
                acc[1][0][nt_] = __builtin_amdgcn_mfma_f32_16x16x32_f16(a1, blo, acc[1][0][nt_], 0, 0, 0); \
                acc[0][1][nt_] = __builtin_amdgcn_mfma_f32_16x16x32_f16(a0, bhi, acc[0][1][nt_], 0, 0, 0); \
                acc[1][1][nt_] = __builtin_amdgcn_mfma_f32_16x16x32_f16(a1, bhi, acc[1][1][nt_], 0, 0, 0); \
            }                                                                \
        }                                                                    \
    }

__global__ __launch_bounds__(256, 3) void conv_histA_kernel(
    const _Float16* __restrict__ xf, const _Float16* __restrict__ wf,
    const _Float16* __restrict__ zbuf, float* __restrict__ pbuf,
    const float* __restrict__ boxes, const float* __restrict__ scales,
    const float* __restrict__ pdls, const float* __restrict__ pdts,
    u32* __restrict__ gpartA)
{
    __shared__ __attribute__((aligned(16))) char smem[51200];
    const int bid = blockIdx.x;
    const int tid = threadIdx.x;
    if (bid >= 768) {
        hist12_256(boxes, scales, pdls, pdts, gpartA, bid - 768, smem, 0, nullptr);
        return;
    }
    _Float16* wS = (_Float16*)smem;            // 18432 B
    _Float16* xS = (_Float16*)(smem + 18432);  // 32768 B
    const int p = bid;
    const int L = (p & 7) * 96 + (p >> 3);
    const int og = L & 7;
    const int t  = L >> 3;
    const int xt = t % 6;
    const int bz = t / 6;
    const int y0 = xt * 8;
    const int b  = bz >> 2, ks = bz & 3;
    const int wv = tid >> 6;
    const int ln = tid & 63;
    const int n  = ln & 15;
    const int q  = ln >> 4;

    f32x4 acc[2][2][3];
#pragma unroll
    for (int mt = 0; mt < 2; ++mt)
#pragma unroll
        for (int rr = 0; rr < 2; ++rr)
#pragma unroll
            for (int nt = 0; nt < 3; ++nt) acc[mt][rr][nt] = (f32x4){0.f, 0.f, 0.f, 0.f};

    const _Float16* wsrc[5];
    const _Float16* xsrc[8];
#pragma unroll
    for (int it = 0; it < 5; ++it) {
        int g = it * 256 + tid;
        int gg = (g < 1152) ? g : 0;
        int tap = gg >> 7, r = gg & 127, qq = r >> 5, oc = r & 31;
        wsrc[it] = wf + (size_t)(((og * 32 + oc) * 9 + tap) * 1024 + qq * 8);
    }
#pragma unroll
    for (int it = 0; it < 8; ++it) {
        int g = it * 256 + tid;
        int row = g / 200, r2 = g - row * 200;
        int qq = r2 / 50, c = r2 - qq * 50;
        int gy = y0 + row - 1, gx = c - 1;
        bool inb = (g < 2000) && ((unsigned)gy < 48u) && ((unsigned)gx < 48u);
        xsrc[it] = inb ? (xf + (size_t)(((b * 48 + gy) * 48 + gx) * 1024 + qq * 8)) : zbuf;
    }

    const int c0 = ks * 256;
    const int rbase = 2 * wv;

    STAGE(c0);

#pragma unroll 1
    for (int ci = 0; ci < 8; ++ci) {
        asm volatile("s_waitcnt vmcnt(0)" ::: "memory");
        __syncthreads();

        __builtin_amdgcn_s_setprio(1);
        f16x8 bA[9], bB[9];
        LDB(bA, rbase + 0);
        LDB(bB, rbase + 1);
        DOTAP(0, bA, bB);
        LDB(bA, rbase + 2);
        DOTAP(3, bB, bA);
        LDB(bB, rbase + 3);
        DOTAP(6, bA, bB);
        __builtin_amdgcn_s_setprio(0);
        __syncthreads();
        if (ci < 7) STAGE(c0 + (ci + 1) * 32);
    }

#pragma unroll
    for (int rr = 0; rr < 2; ++rr) {
        const int y = y0 + 2 * wv + rr;
#pragma unroll
        for (int mt = 0; mt < 2; ++mt) {
#pragma unroll
            for (int nt = 0; nt < 3; ++nt) {
                int x = nt * 16 + n;
                *(f32x4*)(pbuf + (size_t)ks * PSLICE +
                          ((size_t)(b * 48 + y) * 48 + x) * 256 + og * 32 + mt * 16 + q * 4) = acc[mt][rr][nt];
            }
        }
    }
}

// conv_sum: standalone (round-8 form). grid 2304 x 256.
__global__ __launch_bounds__(256) void conv_sum_kernel(
    const float* __restrict__ pbuf, const float* __restrict__ bd,
    _Float16* __restrict__ dec)
{
    size_t idx = (size_t)blockIdx.x * 256 + threadIdx.x;
    size_t e = idx * 4;
    int och = (int)(e & 255);
    f32x4 s0 = *(const f32x4*)(pbuf + e);
    f32x4 s1 = *(const f32x4*)(pbuf + (size_t)PSLICE + e);
    f32x4 s2 = *(const f32x4*)(pbuf + (size_t)2 * PSLICE + e);
    f32x4 s3 = *(const f32x4*)(pbuf + (size_t)3 * PSLICE + e);
    float4 b4 = *(const float4*)(bd + och);
    f16x4 v;
    v.x = (_Float16)fmaxf(s0[0] + s1[0] + s2[0] + s3[0] + b4.x, 0.f);
    v.y = (_Float16)fmaxf(s0[1] + s1[1] + s2[1] + s3[1] + b4.y, 0.f);
    v.z = (_Float16)fmaxf(s0[2] + s1[2] + s2[2] + s3[2] + b4.z, 0.f);
    v.w = (_Float16)fmaxf(s0[3] + s1[3] + s2[3] + s3[3] + b4.w, 0.f);
    *(f16x4*)(dec + e) = v;
}

// ---------------------------------------------------------------------------
// F3: roi+box head (blocks 0..2047) || histB (2048..2303).
// ---------------------------------------------------------------------------
__global__ __launch_bounds__(256) void roi_histB_kernel(
    const _Float16* __restrict__ dec, const float* __restrict__ boxes,
    const float* __restrict__ Wb, const float* __restrict__ bb,
    _Float16* __restrict__ cnn, _Float16* __restrict__ fusion,
    const float* __restrict__ scales, const float* __restrict__ pdls,
    const float* __restrict__ pdts, const u32* __restrict__ meta,
    u32* __restrict__ gpartB)
{
    __shared__ __attribute__((aligned(16))) char smem[20480];
    const int nblk = blockIdx.x;
    if (nblk >= 2048) {
        hist12_256(boxes, scales, pdls, pdts, gpartB, nblk - 2048, smem, 1, meta);
        return;
    }
    int n = nblk; int c = threadIdx.x;
    int b = n >> 9;
    float x1 = boxes[n * 4 + 0], y1 = boxes[n * 4 + 1];
    float x2 = boxes[n * 4 + 2], y2 = boxes[n * 4 + 3];
    // ---- box head ----
    {
        float bf0 = ((x1 + x2) * 0.5f) / 48.f;
        float bf1 = ((y1 + y2) * 0.5f) / 48.f;
        float bf2 = (x2 - x1) / 48.f;
        float bf3 = (y2 - y1) / 48.f;
        float acc = bb[c];
        acc += bf0 * Wb[0 * 256 + c];
        acc += bf1 * Wb[1 * 256 + c];
        acc += bf2 * Wb[2 * 256 + c];
        acc += bf3 * Wb[3 * 256 + c];
        fusion[(size_t)n * 768 + c] = (_Float16)fmaxf(acc, 0.f);
    }
    // ---- roi ----
    float bw = (x2 - x1) * 0.5f, bh = (y2 - y1) * 0.5f;
    float sxv[2] = { x1 + 0.5f * bw, x1 + 1.5f * bw };
    float syv[2] = { y1 + 0.5f * bh, y1 + 1.5f * bh };
    float px[4] = { sxv[0], sxv[1], sxv[0], sxv[1] };
    float py[4] = { syv[0], syv[0], syv[1], syv[1] };
    const _Float16* f = dec + (size_t)b * 2304 * 256;
    f16x4 o4;
    float res[4];
#pragma unroll
    for (int p = 0; p < 4; ++p) {
        float yy = fminf(fmaxf(py[p], 0.f), 47.f);
        float xx = fminf(fmaxf(px[p], 0.f), 47.f);
        int y0 = (int)floorf(yy), x0 = (int)floorf(xx);
        int y1i = min(y0 + 1, 47), x1i = min(x0 + 1, 47);
        float wy = yy - (float)y0, wx = xx - (float)x0;
        float f00 = (float)f[(size_t)(y0 * 48 + x0) * 256 + c];
        float f01 = (float)f[(size_t)(y0 * 48 + x1i) * 256 + c];
        float f10 = (float)f[(size_t)(y1i * 48 + x0) * 256 + c];
        float f11 = (float)f[(size_t)(y1i * 48 + x1i) * 256 + c];
        res[p] = f00 * (1.f - wy) * (1.f - wx) + f01 * (1.f - wy) * wx
               + f10 * wy * (1.f - wx) + f11 * wy * wx;
    }
    o4.x = (_Float16)res[0]; o4.y = (_Float16)res[1];
    o4.z = (_Float16)res[2]; o4.w = (_Float16)res[3];
    *(f16x4*)(cnn + (size_t)n * 1024 + c * 4) = o4;
}

// gemm cnn@WcT -> fusion[:,256:768]: standalone, grid 256.
__global__ __launch_bounds__(256) void gemmcnn_kernel(
    const _Float16* __restrict__ cnn, const _Float16* __restrict__ WcT,
    const _Float16* __restrict__ zbuf, const float* __restrict__ b_cnn,
    _Float16* __restrict__ fusionC)
{
    __shared__ __attribute__((aligned(16))) char smem[16384];
    const int bid = blockIdx.x;
    const int n0 = (bid & 7) * 64, m0 = (bid >> 3) * 64;
    gemm_body<1, _Float16>(cnn, WcT, zbuf, b_cnn, fusionC, 512, 1024, 768, n0, m0,
                           (_Float16*)smem, (_Float16*)(smem + 8192));
}

// ---------------------------------------------------------------------------
// F5: dual gemm fusion@Wg{row,col} -> xw (blocks 0..511) || histC (512..767).
// ---------------------------------------------------------------------------
__global__ __launch_bounds__(256) void gemmz_histC_kernel(
    const _Float16* __restrict__ fusion,
    const _Float16* __restrict__ WgrT, const _Float16* __restrict__ WgcT,
    const _Float16* __restrict__ zbuf,
    float* __restrict__ C0, float* __restrict__ C1,
    const float* __restrict__ boxes, const float* __restrict__ scales,
    const float* __restrict__ pdls, const float* __restrict__ pdts,
    const u32* __restrict__ meta, u32* __restrict__ gpartC)
{
    __shared__ __attribute__((aligned(16))) char smem[16384];
    const int bid = blockIdx.x;
    if (bid >= 512) {
        histC_256(boxes, scales, pdls, pdts, meta, gpartC, bid - 512, smem);
        return;
    }
    const int z = bid >> 8, rem = bid & 255;
    const int n0 = (rem & 7) * 64, m0 = (rem >> 3) * 64;
    gemm_body<0, float>(fusion, z ? WgcT : WgrT, zbuf, nullptr, z ? C1 : C0,
                        512, 768, 512, n0, m0,
                        (_Float16*)smem, (_Float16*)(smem + 8192));
}

// dual classifier-head kernel (leaky 0.01), grid (4,32,2).
__global__ __launch_bounds__(256) void gemm16h_kernel(
    const _Float16* __restrict__ A0, const _Float16* __restrict__ A1,
    const _Float16* __restrict__ Bt0, const _Float16* __restrict__ Bt1,
    const _Float16* __restrict__ zbuf,
    const float* __restrict__ bias0, const float* __restrict__ bias1,
    float* __restrict__ C0, float* __restrict__ C1,
    int M, int N0, int N1, int K)
{
    __shared__ __attribute__((aligned(16))) char smem[16384];
    const int z = blockIdx.z;
    const int N = z ? N1 : N0;
    const int n0 = blockIdx.x * 64, m0 = blockIdx.y * 64;
    if (n0 >= N) return;
    gemm_body<2, float>(z ? A1 : A0, z ? Bt1 : Bt0, zbuf, z ? bias1 : bias0,
                        z ? C1 : C0, N, K, N, n0, m0,
                        (_Float16*)smem, (_Float16*)(smem + 8192));
}

// ---------------------------------------------------------------------------
// 1024-thread scans (round-8 proven form; never in any top-5).
// ---------------------------------------------------------------------------
__global__ __launch_bounds__(1024) void scanA_kernel(
    const u32* __restrict__ gpart, u32* __restrict__ meta)
{
    const int sel = blockIdx.x, tid = threadIdx.x;
    __shared__ u32 bins[4096];
    __shared__ u32 sc[2][1024];
    for (int b = tid; b < 4096; b += 1024) {
        u32 s = 0;
        for (int c = 0; c < NCHUNK; ++c) s += gpart[((size_t)sel * NCHUNK + c) * 4096 + b];
        bins[b] = s;
    }
    __syncthreads();
    u32 part = 0;
#pragma unroll
    for (int j = 0; j < 4; ++j) part += bins[tid * 4 + j];
    sc[0][tid] = part;
    __syncthreads();
    int src = 0;
    for (int st = 1; st < 1024; st <<= 1) {
        sc[1 - src][tid] = sc[src][tid] + (tid >= st ? sc[src][tid - st] : 0);
        __syncthreads(); src = 1 - src;
    }
    u32 inc = sc[src][tid], exc = inc - part;
    if (exc < (u32)KEDGE && (u32)KEDGE <= inc) {
        u32 cum = exc;
        for (int j = 0; j < 4; ++j) {
            u32 c = bins[tid * 4 + j];
            if (cum + c >= (u32)KEDGE) {
                meta[sel * MS + 0] = (u32)(tid * 4 + j);
                meta[sel * MS + 1] = (u32)KEDGE - cum;
                break;
            }
            cum += c;
        }
    }
}

__global__ __launch_bounds__(1024) void scanB_kernel(
    const u32* __restrict__ gpart, u32* __restrict__ meta)
{
    const int sel = blockIdx.x, tid = threadIdx.x;
    const u32 TH = meta[sel * MS + 1];
    __shared__ u32 bins[4096];
    __shared__ u32 sc[2][1024];
    for (int b = tid; b < 4096; b += 1024) {
        u32 s = 0;
        for (int c = 0; c < NCHUNK; ++c) s += gpart[((size_t)sel * NCHUNK + c) * 4096 + b];
        bins[b] = s;
    }
    __syncthreads();
    u32 part = 0;
#pragma unroll
    for (int j = 0; j < 4; ++j) part += bins[tid * 4 + j];
    sc[0][tid] = part;
    __syncthreads();
    int src = 0;
    for (int st = 1; st < 1024; st <<= 1) {
        sc[1 - src][tid] = sc[src][tid] + (tid >= st ? sc[src][tid - st] : 0);
        __syncthreads(); src = 1 - src;
    }
    u32 inc = sc[src][tid], exc = inc - part;
    if (exc < TH && TH <= inc) {
        u32 cum = exc;
        for (int j = 0; j < 4; ++j) {
            u32 c = bins[tid * 4 + j];
            if (cum + c >= TH) {
                meta[sel * MS + 6] = (meta[sel * MS + 0] << 12) | (u32)(tid * 4 + j);
                meta[sel * MS + 7] = TH - cum;
                break;
            }
            cum += c;
        }
    }
}

// scanC: exact q*, then binary-search the w*-tie q-interval [qlo,qhi].
__global__ __launch_bounds__(256) void scanC_kernel(
    const u32* __restrict__ gpart, u32* __restrict__ meta)
{
    const int sel = blockIdx.x, tid = threadIdx.x;
    const u32 TH = meta[sel * MS + 7];
    __shared__ u32 bins[256];
    __shared__ u32 sc[2][256];
    __shared__ u32 s_qstar;
    u32 s = 0;
    for (int c = 0; c < NCHUNK; ++c) s += gpart[((size_t)sel * NCHUNK + c) * 256 + tid];
    bins[tid] = s;
    sc[0][tid] = s;
    __syncthreads();
    int src = 0;
    for (int st = 1; st < 256; st <<= 1) {
        sc[1 - src][tid] = sc[src][tid] + (tid >= st ? sc[src][tid - st] : 0);
        __syncthreads(); src = 1 - src;
    }
    u32 inc = sc[src][tid], exc = inc - bins[tid];
    if (exc < TH && TH <= inc)
        s_qstar = (meta[sel * MS + 6] << 8) | (u32)tid;
    __syncthreads();
    if (tid == 0) {
        u32 prefix = s_qstar;
        float qstar = __uint_as_float(prefix);
        float wstar = (float)exp(-(double)qstar);
        u32 lo = 0, hi = prefix;              // smallest qb with exp(-q)==w*
        while (lo < hi) {
            u32 mid = (lo + hi) >> 1;
            float wm = (float)exp(-(double)__uint_as_float(mid));
            if (wm > wstar) lo = mid + 1; else hi = mid;
        }
        meta[sel * MS + 2] = lo;
        lo = prefix; hi = 0x7F800000u;        // largest qb with exp(-q)==w*
        while (lo < hi) {
            u32 mid = (lo + hi + 1) >> 1;
            float wm = (float)exp(-(double)__uint_as_float(mid));
            if (wm < wstar) hi = mid - 1; else lo = mid;
        }
        meta[sel * MS + 3] = lo;
        meta[sel * MS + 4] = __float_as_uint(wstar);
    }
}

// 1024-thread sv/tb helper for emit.
__device__ __forceinline__ float compute_sv_tb(
    const float* __restrict__ boxes, const float* __restrict__ scales,
    const float* __restrict__ pdls, const float* __restrict__ pdts,
    int b, int t, float* sv, float* red)
{
    int tid = threadIdx.x;
    float pdl = pdls[b], pdt = pdts[b], sc = scales[b];
    if (tid < 512) {
        const float* bx = boxes + (size_t)(b * 512 + tid) * 4;
        float o0 = (bx[0] - pdl) / sc;
        float o1 = (bx[1] - pdt) / sc;
        float o2 = (bx[2] - pdl) / sc;
        float o3 = (bx[3] - pdt) / sc;
        sv[tid]  = (t == 0) ? (o1 + o3) * 0.5f : (o0 + o2) * 0.5f;
        red[tid] = (t == 0) ? fmaxf(o1, o3)    : fmaxf(o0, o2);
    }
    __syncthreads();
    for (int s = 256; s > 0; s >>= 1) {
        if (tid < s) red[tid] = fmaxf(red[tid], red[tid + s]);
        __syncthreads();
    }
    float tbv = red[0];
    __syncthreads();
    return tbv;
}

// ---------------------------------------------------------------------------
// emit: two-pass block-aggregated slot reservation. 32 chunks x 8 sels.
// ---------------------------------------------------------------------------
__global__ __launch_bounds__(1024) void emit_kernel(
    const float* __restrict__ boxes, const float* __restrict__ scales,
    const float* __restrict__ pdls, const float* __restrict__ pdts,
    u32* __restrict__ meta, int* __restrict__ tiebuf, int* __restrict__ tiecnt,
    int* __restrict__ es, int* __restrict__ ed, float* __restrict__ ewt,
    int* __restrict__ indeg, float* __restrict__ degw)
{
    __shared__ float sv[512]; __shared__ float red[512];
    __shared__ int s_wcnt, s_tcnt, s_wbase, s_tbase;
    const int sel = blockIdx.y, b = sel >> 1, t = sel & 1;
    const int tid = threadIdx.x;
    const float tbv = compute_sv_tb(boxes, scales, pdls, pdts, b, t, sv, red);
    const u32 qlo = meta[sel * MS + 2], qhi = meta[sel * MS + 3];
    const int base = t * 16384 + b * 4096;
    const int e0 = blockIdx.x * ECHUNK + tid;
    const int e1 = min((int)(blockIdx.x + 1) * ECHUNK, NE);
    if (tid == 0) { s_wcnt = 0; s_tcnt = 0; }
    __syncthreads();
    int myw = 0, myt = 0;
    for (int e = e0; e < e1; e += 1024) {
        u32 qb; QBITS(e, qb);
        if (qb < qlo) ++myw;
        else if (qb <= qhi) ++myt;
    }
    if (myw) atomicAdd(&s_wcnt, myw);
    if (myt) atomicAdd(&s_tcnt, myt);
    __syncthreads();
    if (tid == 0) {
        s_wbase = (s_wcnt > 0) ? (int)atomicAdd(&meta[sel * MS + 5], (u32)s_wcnt) : 0;
        s_tbase = (s_tcnt > 0) ? atomicAdd(&tiecnt[sel * TS], s_tcnt) : 0;
        s_wcnt = 0; s_tcnt = 0;
    }
    __syncthreads();
    for (int e = e0; e < e1; e += 1024) {
        u32 qb; QBITS(e, qb);
        if (qb < qlo) {
            int i = e / 511; int jj = e - i * 511; int j = jj + (jj >= i ? 1 : 0);
            float wval = (float)exp(-(double)__uint_as_float(qb));
            int slot = s_wbase + atomicAdd(&s_wcnt, 1);
            es[base + slot] = b * 512 + i;
            ed[base + slot] = b * 512 + j;
            ewt[base + slot] = wval;
            atomicAdd(&indeg[t * 2048 + b * 512 + j], 1);
            atomicAdd(&degw[t * 2048 + b * 512 + j], wval);
        } else if (qb <= qhi) {
            int p = s_tbase + atomicAdd(&s_tcnt, 1);
            if (p < TIECAP) tiebuf[sel * TIECAP + p] = e;
        }
    }
}

// ---------------------------------------------------------------------------
// tie resolution + indeg scan + dis + CSR fill. grid 2 (t), block 1024.
// ---------------------------------------------------------------------------
__global__ __launch_bounds__(1024) void tie_scan_fill_kernel(
    u32* __restrict__ meta, const int* __restrict__ tiebuf, const int* __restrict__ tiecnt,
    int* __restrict__ es, int* __restrict__ ed, float* __restrict__ ewt,
    int* __restrict__ indeg, float* __restrict__ degw,
    int* __restrict__ offs, float* __restrict__ dis, int* __restrict__ csr)
{
    __shared__ int bufA[2048], bufB[2048];
    __shared__ int fill_l[2048];
    const int t = blockIdx.x, tid = threadIdx.x;
    for (int b = 0; b < 4; ++b) {
        int sel = b * 2 + t;
        int m = min(tiecnt[sel * TS], TIECAP);
        int r = KEDGE - (int)meta[sel * MS + 5];
        float wt = __uint_as_float(meta[sel * MS + 4]);
        int base = t * 16384 + b * 4096;
        for (int k = tid; k < m; k += 1024) {
            int e = tiebuf[sel * TIECAP + k];
            int rank = 0;
            for (int l = 0; l < m; ++l) rank += (tiebuf[sel * TIECAP + l] < e) ? 1 : 0;
            if (rank < r) {
                int i = e / 511; int jj = e - i * 511; int j = jj + (jj >= i ? 1 : 0);
                int slot = (int)atomicAdd(&meta[sel * MS + 5], 1u);
                es[base + slot] = b * 512 + i;
                ed[base + slot] = b * 512 + j;
                ewt[base + slot] = wt;
                atomicAdd(&indeg[t * 2048 + b * 512 + j], 1);
                atomicAdd(&degw[t * 2048 + b * 512 + j], wt);
            }
        }
    }
    __threadfence();
    __syncthreads();
    // exclusive scan of indeg -> offs (global + LDS copy in bufA)
    bufA[tid] = indeg[t * 2048 + tid];
    bufA[tid + 1024] = indeg[t * 2048 + tid + 1024];
    fill_l[tid] = 0; fill_l[tid + 1024] = 0;
    __syncthreads();
    int* src = bufA; int* dst = bufB;
    for (int st = 1; st < 2048; st <<= 1) {
        dst[tid] = src[tid] + (tid >= st ? src[tid - st] : 0);
        int k1 = tid + 1024;
        dst[k1] = src[k1] + (k1 >= st ? src[k1 - st] : 0);
        __syncthreads();
        int* tmp = src; src = dst; dst = tmp;
    }
    int off0 = (tid == 0) ? 0 : src[tid - 1];
    int off1 = src[tid + 1023];
    __syncthreads();
    // write offs to LDS (reuse dst buffer) + global
    dst[tid] = off0; dst[tid + 1024] = off1;
    offs[t * 2048 + tid] = off0;
    offs[t * 2048 + tid + 1024] = off1;
    dis[t * 2048 + tid] = 1.0f / sqrtf(1.0f + degw[t * 2048 + tid]);
    dis[t * 2048 + tid + 1024] = 1.0f / sqrtf(1.0f + degw[t * 2048 + tid + 1024]);
    __syncthreads();
    // CSR fill over this t's 16384 edges
    for (int e = tid; e < 16384; e += 1024) {
        int dl = ed[t * 16384 + e] & 2047;
        int pos = dst[dl] + atomicAdd(&fill_l[dl], 1);
        csr[t * 16384 + pos] = e;
    }
}

// E7: GCN aggregate -> feats f16
__global__ __launch_bounds__(256) void gcn_agg_kernel(
    const float* __restrict__ xw_row, const float* __restrict__ xw_col,
    const float* __restrict__ b_row, const float* __restrict__ b_col,
    const int* __restrict__ es, const float* __restrict__ ew,
    const int* __restrict__ csr, const int* __restrict__ offs,
    const int* __restrict__ indeg, const float* __restrict__ dis,
    _Float16* __restrict__ feat_row, _Float16* __restrict__ feat_col)
{
    int d = blockIdx.x; int t = blockIdx.y;
    const float* xw = t ? xw_col : xw_row;
    const float* bg = t ? b_col : b_row;
    _Float16* out = t ? feat_col : feat_row;
    int f0 = threadIdx.x, f1 = threadIdx.x + 256;
    float dd = dis[t * 2048 + d];
    float a0 = dd * dd * xw[(size_t)d * 512 + f0];
    float a1 = dd * dd * xw[(size_t)d * 512 + f1];
    int st = offs[t * 2048 + d], cnt = indeg[t * 2048 + d];
    for (int k = 0; k < cnt; ++k) {
        int e = csr[t * 16384 + st + k];
        int s = es[t * 16384 + e];
        float w = ew[t * 16384 + e];
        float coef = dis[t * 2048 + s] * w * dd;
        a0 += coef * xw[(size_t)s * 512 + f0];
        a1 += coef * xw[(size_t)s * 512 + f1];
    }
    a0 += bg[f0]; a1 += bg[f1];
    out[(size_t)d * 512 + f0] = (_Float16)fmaxf(a0, 0.f);
    out[(size_t)d * 512 + f1] = (_Float16)fmaxf(a1, 0.f);
}

// ---------------------------------------------------------------------------
extern "C" void kernel_launch(void* const* d_in, const int* in_sizes, int n_in,
                              void* d_out, int out_size, void* d_ws, size_t ws_size,
                              hipStream_t stream)
{
    const float* x      = (const float*)d_in[0];
    const float* boxes  = (const float*)d_in[1];
    const float* scales = (const float*)d_in[2];
    const float* pdls   = (const float*)d_in[3];
    const float* pdts   = (const float*)d_in[4];
    const float* W_dec  = (const float*)d_in[5];
    const float* b_dec  = (const float*)d_in[6];
    const float* W_box  = (const float*)d_in[7];
    const float* b_box  = (const float*)d_in[8];
    const float* W_cnn  = (const float*)d_in[9];
    const float* b_cnn  = (const float*)d_in[10];
    const float* W_grow = (const float*)d_in[11];
    const float* b_grow = (const float*)d_in[12];
    const float* W_gcol = (const float*)d_in[13];
    const float* b_gcol = (const float*)d_in[14];
    const float* W_rcls = (const float*)d_in[15];
    const float* b_rcls = (const float*)d_in[16];
    const float* W_ccls = (const float*)d_in[17];
    const float* b_ccls = (const float*)d_in[18];

    char* ws = (char*)d_ws;
    size_t off = 0;
    auto alloc = [&](size_t bytes) -> void* {
        void* p = ws + off;
        off = (off + bytes + 255) & ~(size_t)255;
        return p;
    };
    _Float16* xf16   = (_Float16*)alloc((size_t)4 * 2304 * 1024 * 2);  // NHWC in
    _Float16* wf16   = (_Float16*)alloc((size_t)256 * 9216 * 2);       // [o][tap][ch]
    _Float16* dec    = (_Float16*)alloc((size_t)4 * 2304 * 256 * 2);   // NHWC
    float*    pbuf   = (float*)   alloc((size_t)4 * PSLICE * 4);       // split-K(4) partials
    _Float16* cnn    = (_Float16*)alloc((size_t)2048 * 1024 * 2);
    _Float16* fusion = (_Float16*)alloc((size_t)2048 * 768 * 2);
    _Float16* WcT    = (_Float16*)alloc((size_t)512 * 1024 * 2);
    _Float16* WgrT   = (_Float16*)alloc((size_t)512 * 768 * 2);
    _Float16* WgcT   = (_Float16*)alloc((size_t)512 * 768 * 2);
    _Float16* WrT    = (_Float16*)alloc((size_t)228 * 512 * 2);
    _Float16* WccT   = (_Float16*)alloc((size_t)116 * 512 * 2);
    float* xw        = (float*)alloc((size_t)2097152 * 4);             // xw_row|xw_col
    _Float16* feats  = (_Float16*)alloc((size_t)2 * 2048 * 512 * 2);   // row|col
    int*  es     = (int*)  alloc((size_t)2 * 16384 * 4);
    int*  ed     = (int*)  alloc((size_t)2 * 16384 * 4);
    float* ewt   = (float*)alloc((size_t)2 * 16384 * 4);
    int*  offsA  = (int*)  alloc((size_t)4096 * 4);
    float* dis   = (float*)alloc((size_t)4096 * 4);
    int*  csr    = (int*)  alloc((size_t)2 * 16384 * 4);
    int*  tiebuf = (int*)  alloc((size_t)8 * TIECAP * 4);
    u32*  gpartA = (u32*)  alloc((size_t)8 * NCHUNK * 4096 * 4);   // fully overwritten
    u32*  gpartB = (u32*)  alloc((size_t)8 * NCHUNK * 4096 * 4);
    u32*  gpartC = (u32*)  alloc((size_t)8 * NCHUNK * 256 * 4);
    // ---- zero zone (one hipMemsetAsync) ----
    size_t z0 = off;
    u32*  meta   = (u32*)  alloc((size_t)8 * MS * 4);
    int*  tiecnt = (int*)  alloc((size_t)8 * TS * 4);
    int*  indeg  = (int*)  alloc((size_t)4096 * 4);
    float* degw  = (float*)alloc((size_t)4096 * 4);
    _Float16* zbuf = (_Float16*)alloc((size_t)4096);   // zero pad for OOB gl_lds sources
    size_t z1 = off;

    float* out = (float*)d_out;

    hipMemsetAsync(ws + z0, 0, z1 - z0, stream);

    // fused prep: cvt_x (3072) + cvt_w (256) + cvt_t5 (1472)
    prep_kernel<<<4800, 256, 0, stream>>>(x, xf16, W_dec, wf16,
                                          W_cnn, WcT, W_grow, WgrT, W_gcol, WgcT,
                                          W_rcls, WrT, W_ccls, WccT);
    // F1: conv (768) || histA (256)
    conv_histA_kernel<<<1024, 256, 0, stream>>>(xf16, wf16, zbuf, pbuf,
                                                boxes, scales, pdls, pdts, gpartA);
    scanA_kernel<<<8, 1024, 0, stream>>>(gpartA, meta);
    conv_sum_kernel<<<2304, 256, 0, stream>>>(pbuf, b_dec, dec);
    // F3: roi+box (2048) || histB (256)
    roi_histB_kernel<<<2304, 256, 0, stream>>>(dec, boxes, W_box, b_box, cnn, fusion,
                                               scales, pdls, pdts, meta, gpartB);
    scanB_kernel<<<8, 1024, 0, stream>>>(gpartB, meta);
    gemmcnn_kernel<<<256, 256, 0, stream>>>(cnn, WcT, zbuf, b_cnn, fusion + 256);
    // F5: dual gemm xw (512) || histC (256)
    gemmz_histC_kernel<<<768, 256, 0, stream>>>(fusion, WgrT, WgcT, zbuf,
                                                xw, xw + 1048576,
                                                boxes, scales, pdls, pdts, meta, gpartC);
    scanC_kernel<<<8, 256, 0, stream>>>(gpartC, meta);
    emit_kernel<<<dim3(NCHUNK, 8), 1024, 0, stream>>>(boxes, scales, pdls, pdts, meta,
                                                      tiebuf, tiecnt, es, ed, ewt, indeg, degw);
    tie_scan_fill_kernel<<<2, 1024, 0, stream>>>(meta, tiebuf, tiecnt, es, ed, ewt,
                                                 indeg, degw, offsA, dis, csr);
    gcn_agg_kernel<<<dim3(2048, 2), 256, 0, stream>>>(xw, xw + 1048576, b_grow, b_gcol,
                                                      es, ewt, csr, offsA, indeg, dis,
                                                      feats, feats + (size_t)2048 * 512);
    // both classifier heads (leaky 0.01) in one dual launch -> fp32 out
    gemm16h_kernel<<<dim3(4, 32, 2), 256, 0, stream>>>(feats, feats + (size_t)2048 * 512,
                                                       WrT, WccT, zbuf, b_rcls, b_ccls,
                                                       out, out + (size_t)2048 * 228,
                                                       2048, 228, 116, 512);
}